// Round 5
// baseline (169.561 us; speedup 1.0000x reference)
//
#include <hip/hip_runtime.h>
#include <math.h>

// EqualtimeLayer R18 = R17 solver in the R13 resource envelope.
// R17 post-mortem: dur ratio R17/R13 = 1.33 == LDS ratio 16896/12800 = 1.32,
// occupancy 71%->51%. The regression is RESIDENCY (co-resident blocks), which
// scales with LDS footprint; per-block latency was unchanged. Fixes:
//  - NB 512 -> 256 (raw+pck halve; scan halves; mates loop ~+0.4 avg mates).
//  - s_psx: PRE floats -> CHUNK floats (fast path only). Generic + fallback
//    paths (rare) use a bucket-granular suffix-min built into s_raw as
//    scratch (one thread per bucket, then wave-0 reversed-DPP suffix scan,
//    R14/R16-verified), re-zeroed after use.
//  - __launch_bounds__(256, 8) restored: R17 measured 40 VGPR < 64 cap, so
//    no R15-style spill. WRITE_SIZE is the tripwire.
// Total LDS ~11.3 KB (< R13's 12.8). Fast path: 5 barriers/batch.

#define B_TOT 32
#define PRE 1024
#define POST 1024
#define NB 256
#define TPB 256
#define EPT 4
#define BPW 8
#define CHUNK 256
#define TCUTF 0.625f
#define BSCALE 409.6f          // 256 buckets over [0, 0.625)
#define BSCALE2 186.18181818f  // 256 buckets over [0.625, 2.0)
#define INFB 0x7F800000

// ---- DPP helpers (gfx9 encodings) ----
template<int CTRL, int MASK>
__device__ __forceinline__ int dpp_add_i32(int v) {
    return v + __builtin_amdgcn_update_dpp(0, v, CTRL, MASK, 0xf, true);
}
template<int CTRL, int MASK>
__device__ __forceinline__ float dpp_add_f32(float v) {
    int t = __builtin_amdgcn_update_dpp(0, __float_as_int(v), CTRL, MASK, 0xf, true);
    return v + __int_as_float(t);
}
template<int CTRL, int MASK>
__device__ __forceinline__ int dpp_min_i32(int v) {
    // old = +INF bits, bound_ctrl=false: missing lanes contribute min identity
    int t = __builtin_amdgcn_update_dpp(INFB, v, CTRL, MASK, 0xf, false);
    return min(v, t);
}
template<int CTRL>
__device__ __forceinline__ float dpp_min_f32(float v) {
    int t = __builtin_amdgcn_update_dpp(__float_as_int(v), __float_as_int(v), CTRL, 0xf, 0xf, false);
    return fminf(v, __int_as_float(t));
}
__device__ __forceinline__ int wave_iscan_i32(int v) {
    v = dpp_add_i32<0x111, 0xf>(v);
    v = dpp_add_i32<0x112, 0xf>(v);
    v = dpp_add_i32<0x114, 0xf>(v);
    v = dpp_add_i32<0x118, 0xf>(v);
    v = dpp_add_i32<0x142, 0xa>(v);
    v = dpp_add_i32<0x143, 0xc>(v);
    return v;
}
__device__ __forceinline__ float wave_iscan_f32(float v) {
    v = dpp_add_f32<0x111, 0xf>(v);
    v = dpp_add_f32<0x112, 0xf>(v);
    v = dpp_add_f32<0x114, 0xf>(v);
    v = dpp_add_f32<0x118, 0xf>(v);
    v = dpp_add_f32<0x142, 0xa>(v);
    v = dpp_add_f32<0x143, 0xc>(v);
    return v;
}
__device__ __forceinline__ int wave_iscan_min_i32(int v) {
    v = dpp_min_i32<0x111, 0xf>(v);
    v = dpp_min_i32<0x112, 0xf>(v);
    v = dpp_min_i32<0x114, 0xf>(v);
    v = dpp_min_i32<0x118, 0xf>(v);
    v = dpp_min_i32<0x142, 0xa>(v);
    v = dpp_min_i32<0x143, 0xc>(v);
    return v;
}
__device__ __forceinline__ float wave_min_f32(float v) {
    v = fminf(v, __shfl_down(v, 32));
    v = fminf(v, __shfl_down(v, 16));
    v = dpp_min_f32<0x140>(v);
    v = dpp_min_f32<0x141>(v);
    v = dpp_min_f32<0x4E>(v);
    v = dpp_min_f32<0xB1>(v);
    return v;
}
// In-wave INCLUSIVE suffix-min of t (>=0) over lanes >= own lane.
__device__ __forceinline__ float wave_suffix_min_f32(float t, int lane) {
    int rv = __shfl(__float_as_int(t), 63 - lane);   // reverse
    int is = wave_iscan_min_i32(rv);                 // inclusive fwd min
    return __int_as_float(__shfl(is, 63 - lane));    // reverse back
}
__device__ __forceinline__ int clampb(int k) {
    return k < 0 ? 0 : (k > NB - 1 ? NB - 1 : k);
}

// Wave-0-only: exclusive scan of NB=256 counts (raw -> pck, off<<12|cnt),
// total -> *nout. One int4 per lane, conflict-free.
__device__ __forceinline__ void scan_counts(const int* raw, int* pck,
                                            int* nout, int lane) {
    int4 a = reinterpret_cast<const int4*>(raw)[lane];
    int c[4] = {a.x, a.y, a.z, a.w};
    int le[4]; int s = 0;
#pragma unroll
    for (int j = 0; j < 4; ++j) { le[j] = s; s += c[j]; }
    int x = wave_iscan_i32(s);
    int e = x - s;                     // exclusive over groups
    int o[4];
#pragma unroll
    for (int j = 0; j < 4; ++j) o[j] = ((e + le[j]) << 12) | c[j];
    reinterpret_cast<int4*>(pck)[lane] = make_int4(o[0], o[1], o[2], o[3]);
    if (lane == 0) *nout = __builtin_amdgcn_readlane(x, 63);
}

// Rare-path helpers: bucket min-time into sfx_raw (one thread per bucket,
// plain write), then wave-0 in-place suffix-min (min over buckets STRICTLY
// later; R14/R16-verified reversed-scan pattern).
__device__ __forceinline__ void bucket_min_pass(const float* s_t, const int* pck,
                                                int* sfx_raw, int baseOff, int tid) {
    int pk = pck[tid];
    int bas = (pk >> 12) + baseOff, cn = pk & 0xfff;
    int m = INFB;
    for (int q = bas; q < bas + cn; ++q)
        m = min(m, __float_as_int(s_t[q]));          // t>=0: bit order == float order
    sfx_raw[tid] = m;
}
__device__ __forceinline__ void suffix_pass(int* sfx_raw, int lane) {
    int4 a = reinterpret_cast<const int4*>(sfx_raw)[lane];
    int m[4] = {a.x, a.y, a.z, a.w};
    int g = min(min(m[0], m[1]), min(m[2], m[3]));
    int rg = __shfl(g, 63 - lane);
    int im = wave_iscan_min_i32(rg);
    int pm = __shfl_up(im, 1);
    int er = (lane == 0) ? INFB : pm;
    int sg = __shfl(er, 63 - lane);                  // min over groups > lane
    int f[4];
    f[3] = sg;
    f[2] = min(m[3], f[3]);
    f[1] = min(m[2], f[2]);
    f[0] = min(m[1], f[1]);
    reinterpret_cast<int4*>(sfx_raw)[lane] = make_int4(f[0], f[1], f[2], f[3]);
}

// Generic chunked solver (rare: N_low > 256 or fallback tail). Position-order
// block scans + mates correction; tnx from bucket-level sfx.
__device__ __forceinline__ void solve_generic(
    const float* s_t, const float* s_w, const int* pck, const int* sfx,
    float* s_fw, float* s_fwt,
    int cStart, int cEnd, int posLo, int posValidEnd,
    float t0f, float bscale, int baseOff, float tEnd, float theta,
    int tid, int lane, int wid, float& cumW, float& cumWT, float& mloc)
{
    for (int c0 = cStart; c0 < cEnd; c0 += CHUNK) {
        int p = c0 + tid;
        float t_p = s_t[p];
        float w_p = (p >= posLo) ? s_w[p] : 0.f;
        float xw  = wave_iscan_f32(w_p);
        float xwt = wave_iscan_f32(w_p * t_p);
        if (lane == 63) { s_fw[wid] = xw; s_fwt[wid] = xwt; }
        __syncthreads();                               // partials visible
        float W = cumW, WT = cumWT;
        for (int k2 = 0; k2 < wid; ++k2) { W += s_fw[k2]; WT += s_fwt[k2]; }
        W += xw; WT += xwt;                            // inclusive @ p (pos order)
        cumW  += s_fw[0] + s_fw[1] + s_fw[2] + s_fw[3];
        cumWT += s_fwt[0] + s_fwt[1] + s_fwt[2] + s_fwt[3];

        if (p >= posLo && p < posValidEnd) {
            int k = clampb((int)((t_p - t0f) * bscale));
            int pk = pck[k];
            int bas = (pk >> 12) + baseOff, cn = pk & 0xfff;
            float tnx = fminf(__int_as_float(sfx[k]), tEnd);
            if (cn > 1) {
                for (int q2 = bas; q2 < bas + cn; ++q2) {
                    if (q2 == p) continue;
                    float tq = s_t[q2], wq = s_w[q2];
                    bool earlier = (tq < t_p) || (tq == t_p && q2 < p);
                    bool posb = (q2 < p);
                    W  += (earlier ? wq      : 0.f) - (posb ? wq      : 0.f);
                    WT += (earlier ? wq * tq : 0.f) - (posb ? wq * tq : 0.f);
                    if (!earlier) tnx = fminf(tnx, tq);
                }
            }
            if (W > 0.f) {
                float tmp = (theta + WT) * __builtin_amdgcn_rcpf(W);
                if (tmp >= t_p && tmp <= tnx) mloc = fminf(mloc, tmp);
            }
        }
        if (c0 + CHUNK < cEnd) __syncthreads();        // protect s_fw reuse
    }
}

__device__ __forceinline__ float block_min(float v, float* s_red, int lane, int wid) {
    v = wave_min_f32(v);
    if (lane == 0) s_red[wid] = v;
    __syncthreads();
    return fminf(fminf(s_red[0], s_red[1]), fminf(s_red[2], s_red[3]));
}

__global__ __launch_bounds__(TPB, 8) void equaltime_kernel(
    const float* __restrict__ spikes,     // [B][PRE]
    const float* __restrict__ weights,    // [PRE][POST]
    const float* __restrict__ delays,     // [PRE][POST]
    const float* __restrict__ thresholds, // [POST]
    float* __restrict__ out)              // [B][POST]
{
    __shared__ __align__(16) float s_t[PRE];      // 4 KB
    __shared__ __align__(16) float s_w[PRE];      // 4 KB
    __shared__ __align__(16) int   s_raw[NB];     // 1 KB counts / sfx scratch
    __shared__ __align__(16) int   s_pck[NB];     // 1 KB packed (off<<12|cnt)
    __shared__ __align__(16) float s_psx[CHUNK];  // 1 KB fast-path suffix
    __shared__ float s_fw[4], s_fwt[4], s_fmn[4];
    __shared__ float s_red[4];
    __shared__ int   s_nlow;

    const int tid  = threadIdx.x;
    const int lane = tid & 63;
    const int wid  = tid >> 6;

    // XCD-contiguous swizzle for weight/delay L2 locality
    const int bx   = blockIdx.x;
    const int sbx  = (bx & 7) * 512 + (bx >> 3);
    const int post = sbx >> 2;            // 4 WGs per post
    const int b0   = (sbx & 3) * BPW;
    const float theta = thresholds[post];

    float dly[EPT], wgt[EPT];
#pragma unroll
    for (int j = 0; j < EPT; ++j) {
        int pre = tid * EPT + j;
        dly[j] = delays[pre * POST + post];
        wgt[j] = weights[pre * POST + post];
    }

    // init counts once (re-inits folded into each batch's phases)
    if (tid < 64)
        reinterpret_cast<int4*>(s_raw)[tid] = make_int4(0, 0, 0, 0);
    __syncthreads();

    for (int bi = 0; bi < BPW; ++bi) {
        const int b = b0 + bi;

        // ---- times; hist (count only) of t<TCUT; min of the rest ----
        float4 sp = *reinterpret_cast<const float4*>(spikes + b * PRE + tid * EPT);
        float tv[EPT] = {sp.x + dly[0], sp.y + dly[1], sp.z + dly[2], sp.w + dly[3]};
        int bkt[EPT], rnk[EPT];
        float mloc = INFINITY;
#pragma unroll
        for (int j = 0; j < EPT; ++j) {
            int k = (int)(tv[j] * BSCALE);
            bkt[j] = k;
            if (k < NB) rnk[j] = atomicAdd(&s_raw[k], 1);
            else        mloc = fminf(mloc, tv[j]);
        }
        mloc = wave_min_f32(mloc);
        __syncthreads();                               // B1: hist final

        if (lane == 0) s_red[wid] = mloc;              // read post-B2
        if (wid == 0) scan_counts(s_raw, s_pck, &s_nlow, lane);
        __syncthreads();                               // B2: pck/nlow/s_red

        const int N_low = s_nlow;
        const float minExcl = fminf(fminf(s_red[0], s_red[1]),
                                    fminf(s_red[2], s_red[3]));

        // ---- scatter (arrival order in bucket); zero raw; pad holes ----
#pragma unroll
        for (int j = 0; j < EPT; ++j) {
            if (bkt[j] < NB) {
                int pos = (s_pck[bkt[j]] >> 12) + rnk[j];
                s_t[pos] = tv[j];
                s_w[pos] = wgt[j];
            }
        }
        if (wid == 1)   // s_raw reads done at B2; 64 int4 = 256 ints
            reinterpret_cast<int4*>(s_raw)[lane] = make_int4(0, 0, 0, 0);
        const int roundup = (N_low + CHUNK - 1) & ~(CHUNK - 1);
        int h = N_low + tid;
        if (h < roundup) { s_t[h] = minExcl; s_w[h] = 0.f; }
        __syncthreads();                               // B3: scatter+zero visible

        float cumW = 0.f, cumWT = 0.f, mcand = INFINITY;

        if (roundup == CHUNK) {
            // ==== fused fast path: one chunk, suffix fused into scan ====
            const int p = tid;
            float t_p = s_t[p];
            float w_p = s_w[p];                        // pad has w=0
            float xw  = wave_iscan_f32(w_p);
            float xwt = wave_iscan_f32(w_p * t_p);
            float sx  = wave_suffix_min_f32(t_p, lane);
            s_psx[p] = sx;                             // in-wave suffix only
            if (lane == 63) { s_fw[wid] = xw; s_fwt[wid] = xwt; }
            if (lane == 0)  s_fmn[wid] = sx;           // wave's total min
            __syncthreads();                           // B4: partials+psx

            float W = 0.f, WT = 0.f;
            for (int k2 = 0; k2 < wid; ++k2) { W += s_fw[k2]; WT += s_fwt[k2]; }
            W += xw; WT += xwt;
            cumW  = s_fw[0] + s_fw[1] + s_fw[2] + s_fw[3];
            cumWT = s_fwt[0] + s_fwt[1] + s_fwt[2] + s_fwt[3];

            if (p < N_low) {
                int k = (int)(t_p * BSCALE);           // real event => k < NB
                int pk = s_pck[k];
                int bas = pk >> 12, cn = pk & 0xfff;
                int q = bas + cn;
                float tnx = minExcl;
                if (q < CHUNK) {
                    float v = s_psx[q];                // covers q..its wave end
                    for (int w = (q >> 6) + 1; w < 4; ++w)
                        v = fminf(v, s_fmn[w]);        // later waves
                    tnx = fminf(v, minExcl);
                }
                if (cn > 1) {
                    for (int q2 = bas; q2 < bas + cn; ++q2) {
                        if (q2 == p) continue;
                        float tq = s_t[q2], wq = s_w[q2];
                        bool earlier = (tq < t_p) || (tq == t_p && q2 < p);
                        bool posb = (q2 < p);
                        W  += (earlier ? wq      : 0.f) - (posb ? wq      : 0.f);
                        WT += (earlier ? wq * tq : 0.f) - (posb ? wq * tq : 0.f);
                        if (!earlier) tnx = fminf(tnx, tq);
                    }
                }
                if (W > 0.f) {
                    float tmp = (theta + WT) * __builtin_amdgcn_rcpf(W);
                    if (tmp >= t_p && tmp <= tnx) mcand = tmp;
                }
            }
        } else {
            // ==== generic low path (N_low > 256, rare): bucket-sfx in s_raw ====
            if (roundup > 0) {
                bucket_min_pass(s_t, s_pck, s_raw, 0, tid);
                __syncthreads();                       // minT visible
                if (wid == 0) suffix_pass(s_raw, lane);
                __syncthreads();                       // sfx visible
                solve_generic(s_t, s_w, s_pck, s_raw, s_fw, s_fwt,
                              0, roundup, 0, N_low, 0.f, BSCALE, 0,
                              minExcl, theta,
                              tid, lane, wid, cumW, cumWT, mcand);
                __syncthreads();                       // sfx reads done
            }
            if (wid == 1)                              // restore zero for hist
                reinterpret_cast<int4*>(s_raw)[lane] = make_int4(0, 0, 0, 0);
        }
        float mAll = block_min(mcand, s_red, lane, wid);  // B5 (publishes zero)

        // ---- rare exact fallback: no valid crossing among t < TCUT ----
        if (!(mAll < INFINITY) && N_low < PRE) {
#pragma unroll
            for (int j = 0; j < EPT; ++j) {
                if (bkt[j] >= NB) {
                    int k2 = clampb((int)((tv[j] - TCUTF) * BSCALE2));
                    bkt[j] = NB + k2;                  // remember tail bucket
                    rnk[j] = atomicAdd(&s_raw[k2], 1);
                }
            }
            __syncthreads();                           // tail hist final
            if (wid == 0) scan_counts(s_raw, s_pck, &s_nlow, lane);
            __syncthreads();                           // pck visible
#pragma unroll
            for (int j = 0; j < EPT; ++j) {
                if (bkt[j] >= NB) {
                    int pos = N_low + (s_pck[bkt[j] - NB] >> 12) + rnk[j];
                    s_t[pos] = tv[j];
                    s_w[pos] = wgt[j];
                }
            }
            __syncthreads();                           // scatter visible
            bucket_min_pass(s_t, s_pck, s_raw, N_low, tid); // counts now dead
            __syncthreads();                           // minT visible
            if (wid == 0) suffix_pass(s_raw, lane);
            __syncthreads();                           // sfx visible
            solve_generic(s_t, s_w, s_pck, s_raw, s_fw, s_fwt,
                          N_low & ~(CHUNK - 1), PRE, N_low, PRE,
                          TCUTF, BSCALE2, N_low, INFINITY, theta,
                          tid, lane, wid, cumW, cumWT, mcand);
            __syncthreads();                           // sfx reads done
            if (wid == 1)                              // restore zero
                reinterpret_cast<int4*>(s_raw)[lane] = make_int4(0, 0, 0, 0);
            mAll = block_min(mcand, s_red, lane, wid); // publishes zero
        }

        if (tid == 0) out[b * POST + post] = mAll;
        // No trailing barrier: next batch's hist atomics target s_raw, whose
        // zeroing was barrier-ordered before any post-barrier reader.
    }
}

extern "C" void kernel_launch(void* const* d_in, const int* in_sizes, int n_in,
                              void* d_out, int out_size, void* d_ws, size_t ws_size,
                              hipStream_t stream) {
    const float* spikes     = (const float*)d_in[0]; // [32,1024]
    const float* weights    = (const float*)d_in[1]; // [1024,1024]
    const float* delays     = (const float*)d_in[2]; // [1024,1024]
    const float* thresholds = (const float*)d_in[3]; // [1024]
    float* outp = (float*)d_out;                     // [32,1024]

    dim3 grid(POST * (B_TOT / BPW)); // 4096 workgroups
    dim3 block(TPB);
    equaltime_kernel<<<grid, block, 0, stream>>>(spikes, weights, delays, thresholds, outp);
}